// Round 1
// 431.301 us; speedup vs baseline: 1.0138x; 1.0138x over previous
//
#include <hip/hip_runtime.h>
#include <math.h>

// LinearAttention B=16 L=8192 D=256 H=4 dh=32
//   gemm1 (split-bf16 MFMA, fused fp32->hi/lo via v_cvt_pk_bf16_f32): qkv = x@W_qkv
//     colblk 0 -> q hi/lo bf16 [BL,128]
//     colblk 1 -> k fp32 into kvhb[bh][l][0..31]
//     colblk 2 -> v fp32 into kvhb[bh][l][32..63]   (head-blocked: contiguous per (b,h))
//     grid is XCD-grouped: the 3 col-blocks of one row-block share an XCD's L2
//   ksum (no max-subtraction; k~N(0,1) so exp is safe): S[d,e]=sum_l e^k v, Z_d=sum_l e^k
//   combine: M2T[b][n][c] = scale * (S/Z) @ W_out   (split hi/lo bf16)
//   gemm2 (split-bf16 MFMA): out[b] = q[b]@M2[b] + b_out
// Split precision: a=hi+lo; keep Ah*Bh+Ah*Bl+Al*Bh (drop ~2^-18 Al*Bl term).
// Staging: global_load_lds width=16, XOR-swizzled source so frag ds_read_b128
// are <=2-way bank aliased (free).

#define BL 131072

typedef __attribute__((ext_vector_type(8))) short bf16x8;
typedef __attribute__((ext_vector_type(4))) float f32x4;
typedef __attribute__((ext_vector_type(4))) unsigned u32x4;

// packed fp32 pair -> 2x bf16 (RNE), src0 -> bits [15:0]
__device__ __forceinline__ unsigned cvt_pk2(float a, float b) {
    unsigned r;
    asm("v_cvt_pk_bf16_f32 %0, %1, %2" : "=v"(r) : "v"(a), "v"(b));
    return r;
}
__device__ __forceinline__ ushort bf16_rn(float f) {
    return (ushort)cvt_pk2(f, f);
}
__device__ __forceinline__ float bf16f(ushort h) { return __uint_as_float(((unsigned)h) << 16); }

__device__ __forceinline__ void glds16(const void* g, void* l) {
    __builtin_amdgcn_global_load_lds((const __attribute__((address_space(1))) unsigned int*)g,
                                     (__attribute__((address_space(3))) unsigned int*)l,
                                     16, 0, 0);
}

__global__ __launch_bounds__(256) void init_stats(float* S, float* Z) {
    int i = blockIdx.x * 256 + threadIdx.x;
    if (i < 65536) S[i] = 0.f;
    if (i < 2048) Z[i] = 0.f;
}

// W_qkv [256,384] -> WT hi/lo bf16 [384,256]
__global__ __launch_bounds__(256) void convert_w(const float* __restrict__ W,
                                                 ushort* __restrict__ wh,
                                                 ushort* __restrict__ wl) {
    int n = blockIdx.x, k = threadIdx.x;
    float f = W[k * 384 + n];
    ushort h = bf16_rn(f);
    wh[n * 256 + k] = h;
    wl[n * 256 + k] = bf16_rn(f - bf16f(h));
}

// gemm1: [131072x256] @ [256x384], A fp32 (split in-kernel), B=WT hi/lo bf16.
// grid 3072 (1D): wg -> xcd = wg&7, slot = wg>>3, cb = slot%3, yb = (slot/3)*8+xcd.
// The 3 col-blocks (q/k/v) of one row-block map to the SAME xcd -> X L2-reuse.
__global__ __launch_bounds__(256) void gemm1_kernel(
    const float* __restrict__ X,
    const ushort* __restrict__ Wh, const ushort* __restrict__ Wl,
    ushort* __restrict__ Qh, ushort* __restrict__ Ql,
    float* __restrict__ KV) {
    __shared__ __align__(16) float  As[4096];   // 128 rows x 32 k fp32, chunk p = q ^ (r&7)
    __shared__ __align__(16) ushort Bsh[4096];  // 128 rows x 32 k bf16, chunk p = q ^ ((r>>1)&3)
    __shared__ __align__(16) ushort Bsl[4096];
    const int tid = threadIdx.x;
    const int wg = blockIdx.x;
    const int xcd = wg & 7;
    const int slot = wg >> 3;
    const int cb = slot % 3;
    const int yb = (slot / 3) * 8 + xcd;
    const int col0 = cb * 128;
    const int row0 = yb * 128;
    const int lane = tid & 63, wave = tid >> 6;
    const int wr = (wave & 1) * 64, wc = (wave >> 1) * 64;
    const int m = lane & 15, quad = lane >> 4;
    const int ra = lane >> 3, pa = lane & 7;   // A staging: 8 rows/seg, 8 chunks(16B)/row
    const int rb = lane >> 2, pb = lane & 3;   // B staging: 16 rows/seg, 4 chunks/row

    f32x4 acc[4][4] = {};

    for (int k0 = 0; k0 < 256; k0 += 32) {
#pragma unroll
        for (int s = 0; s < 4; ++s) {          // A: 16 segs of 1KB
            int seg = s * 4 + wave;
            int r = seg * 8 + ra;
            int q = pa ^ (r & 7);
            glds16(&X[(long)(row0 + r) * 256 + k0 + q * 4], &As[seg * 256]);
        }
#pragma unroll
        for (int s = 0; s < 2; ++s) {          // Bh/Bl: 8 segs each
            int seg = s * 4 + wave;
            int r = seg * 16 + rb;
            int q = pb ^ ((r >> 1) & 3);
            glds16(&Wh[(long)(col0 + r) * 256 + k0 + q * 8], &Bsh[seg * 512]);
            glds16(&Wl[(long)(col0 + r) * 256 + k0 + q * 8], &Bsl[seg * 512]);
        }
        __syncthreads();

        bf16x8 bh[4], bl[4];
#pragma unroll
        for (int i = 0; i < 4; ++i) {
            int r = wc + i * 16 + m;
            int p = quad ^ ((r >> 1) & 3);
            bh[i] = *(const bf16x8*)&Bsh[r * 32 + p * 8];
            bl[i] = *(const bf16x8*)&Bsl[r * 32 + p * 8];
        }
#pragma unroll
        for (int i = 0; i < 4; ++i) {
            int r = wr + i * 16 + m;
            int p0 = (quad * 2) ^ (r & 7);
            int p1 = (quad * 2 + 1) ^ (r & 7);
            f32x4 a0 = *(const f32x4*)&As[r * 32 + p0 * 4];
            f32x4 a1 = *(const f32x4*)&As[r * 32 + p1 * 4];
            u32x4 ahw, alw;
#pragma unroll
            for (int e = 0; e < 2; ++e) {
                float f0 = a0[2 * e], f1 = a0[2 * e + 1];
                unsigned h = cvt_pk2(f0, f1);
                ahw[e] = h;
                alw[e] = cvt_pk2(f0 - __uint_as_float(h << 16),
                                 f1 - __uint_as_float(h & 0xFFFF0000u));
            }
#pragma unroll
            for (int e = 0; e < 2; ++e) {
                float f0 = a1[2 * e], f1 = a1[2 * e + 1];
                unsigned h = cvt_pk2(f0, f1);
                ahw[2 + e] = h;
                alw[2 + e] = cvt_pk2(f0 - __uint_as_float(h << 16),
                                     f1 - __uint_as_float(h & 0xFFFF0000u));
            }
            bf16x8 ah = __builtin_bit_cast(bf16x8, ahw);
            bf16x8 al = __builtin_bit_cast(bf16x8, alw);
#pragma unroll
            for (int j = 0; j < 4; ++j) {
                acc[i][j] = __builtin_amdgcn_mfma_f32_16x16x32_bf16(ah, bh[j], acc[i][j], 0, 0, 0);
                acc[i][j] = __builtin_amdgcn_mfma_f32_16x16x32_bf16(ah, bl[j], acc[i][j], 0, 0, 0);
                acc[i][j] = __builtin_amdgcn_mfma_f32_16x16x32_bf16(al, bh[j], acc[i][j], 0, 0, 0);
            }
        }
        __syncthreads();
    }

    if (cb == 0) {                   // q -> hi/lo bf16 [BL,128]
#pragma unroll
        for (int i = 0; i < 4; ++i)
#pragma unroll
            for (int r4 = 0; r4 < 4; ++r4) {
                long row = row0 + wr + i * 16 + quad * 4 + r4;
#pragma unroll
                for (int j = 0; j < 4; ++j) {
                    float v = acc[i][j][r4];
                    int col = wc + j * 16 + m;
                    ushort h = bf16_rn(v);
                    Qh[row * 128 + col] = h;
                    Ql[row * 128 + col] = bf16_rn(v - bf16f(h));
                }
            }
    } else {                         // k (cb=1) / v (cb=2) -> kvhb[bh][l][64]
        int vofs = (cb == 2) ? 32 : 0;
#pragma unroll
        for (int i = 0; i < 4; ++i)
#pragma unroll
            for (int r4 = 0; r4 < 4; ++r4) {
                long row = row0 + wr + i * 16 + quad * 4 + r4;
                long b = row >> 13, l = row & 8191;
#pragma unroll
                for (int j = 0; j < 4; ++j) {
                    int c = wc + j * 16 + m;
                    int h = c >> 5, dd = c & 31;
                    KV[(((b * 4 + h) * 8192 + l) * 64) + vofs + dd] = acc[i][j][r4];
                }
            }
    }
}

// S[d,e] = sum_l e^{k[l,d]} v[l,e]; Z_d = sum_l e^{k}. grid = bh*8+chunk (512 blocks).
__global__ __launch_bounds__(256) void ksum_hb(const float* __restrict__ KV,
                                               float* __restrict__ S,
                                               float* __restrict__ Z) {
    int bx = blockIdx.x;
    int c = bx & 7, bh = bx >> 3;
    const float* slab = KV + ((long)bh * 8192 + c * 1024) * 64;
    __shared__ float tile[64][68];
    const int tid = threadIdx.x;
    const int dcol = tid & 31;
    const int e0 = (tid >> 5) * 4;
    const int c4 = tid & 15, lrow = tid >> 4;   // loader: float4 id = u*256+tid
    float z = 0.f;
    f32x4 acc = {0.f, 0.f, 0.f, 0.f};

    for (int t0 = 0; t0 < 1024; t0 += 64) {
#pragma unroll
        for (int u = 0; u < 4; ++u) {
            int l = u * 16 + lrow;
            float4 w = *(const float4*)&slab[((long)(t0 + l)) * 64 + c4 * 4];
            if (c4 < 8) { w.x = __expf(w.x); w.y = __expf(w.y); w.z = __expf(w.z); w.w = __expf(w.w); }
            *(float4*)&tile[l][c4 * 4] = w;
        }
        __syncthreads();
#pragma unroll 8
        for (int l = 0; l < 64; ++l) {
            float e = tile[l][dcol];
            f32x4 vv = *(const f32x4*)&tile[l][32 + e0];
            z += e;
            acc[0] += e * vv[0]; acc[1] += e * vv[1];
            acc[2] += e * vv[2]; acc[3] += e * vv[3];
        }
        __syncthreads();
    }
    if (tid < 32) atomicAdd(&Z[bh * 32 + dcol], z);
#pragma unroll
    for (int j = 0; j < 4; ++j)
        atomicAdd(&S[((long)bh * 32 + dcol) * 32 + e0 + j], acc[j]);
}

// M2T[b][n][h*32+d] = scale * (S[d,e]/Z_d) @ W_out[h*32+e, n], split hi/lo. grid B*H.
__global__ __launch_bounds__(256) void combine_kernel(const float* __restrict__ S,
                                                      const float* __restrict__ Z,
                                                      const float* __restrict__ Wout,
                                                      ushort* __restrict__ m2h,
                                                      ushort* __restrict__ m2l) {
    int bh = blockIdx.x;
    int b = bh >> 2, h = bh & 3;
    int n = threadIdx.x;
    __shared__ float ctx[32][32];
    __shared__ float zs[32];
    if (n < 32) zs[n] = Z[bh * 32 + n];
    __syncthreads();
#pragma unroll
    for (int t = 0; t < 4; ++t) {
        int idx = t * 256 + n;
        int d = idx >> 5, e = idx & 31;
        ctx[d][e] = S[(long)bh * 1024 + idx] / zs[d];
    }
    __syncthreads();
    const float scale = 0.17677669529663687f; // 1/sqrt(32)
    float acc[32];
#pragma unroll
    for (int d = 0; d < 32; ++d) acc[d] = 0.f;
    for (int e = 0; e < 32; ++e) {
        float w = Wout[(h * 32 + e) * 256 + n];
#pragma unroll
        for (int d = 0; d < 32; ++d) acc[d] += ctx[d][e] * w;
    }
#pragma unroll
    for (int d = 0; d < 32; ++d) {
        float v = acc[d] * scale;
        long idx = ((long)(b * 256 + n)) * 128 + h * 32 + d;
        ushort hh = bf16_rn(v);
        m2h[idx] = hh;
        m2l[idx] = bf16_rn(v - bf16f(hh));
    }
}

// gemm2: per-b [8192x128] @ [128x256] + bias. A=q hi/lo, B=M2T hi/lo (both [N][K] bf16).
// grid (2, 64, 16).
__global__ __launch_bounds__(256) void gemm2_kernel(
    const ushort* __restrict__ Ahp, const ushort* __restrict__ Alp,
    const ushort* __restrict__ Bhp, const ushort* __restrict__ Blp,
    const float* __restrict__ bias, float* __restrict__ out) {
    __shared__ __align__(16) ushort Ash[4096];
    __shared__ __align__(16) ushort Asl[4096];
    __shared__ __align__(16) ushort Bsh[4096];
    __shared__ __align__(16) ushort Bsl[4096];
    const int tid = threadIdx.x;
    const int col0 = blockIdx.x * 128;
    const int row0 = blockIdx.y * 128;
    const long bz = blockIdx.z;
    const ushort* Ah = Ahp + bz * (8192L * 128);
    const ushort* Al = Alp + bz * (8192L * 128);
    const ushort* Bh = Bhp + bz * (256L * 128);
    const ushort* Bl = Blp + bz * (256L * 128);
    const int lane = tid & 63, wave = tid >> 6;
    const int wr = (wave & 1) * 64, wc = (wave >> 1) * 64;
    const int m = lane & 15, quad = lane >> 4;
    const int rb = lane >> 2, pb = lane & 3;

    f32x4 acc[4][4] = {};

    for (int k0 = 0; k0 < 128; k0 += 32) {
#pragma unroll
        for (int s = 0; s < 2; ++s) {
            int seg = s * 4 + wave;
            int r = seg * 16 + rb;
            int q = pb ^ ((r >> 1) & 3);
            glds16(&Ah[(long)(row0 + r) * 128 + k0 + q * 8], &Ash[seg * 512]);
            glds16(&Al[(long)(row0 + r) * 128 + k0 + q * 8], &Asl[seg * 512]);
            glds16(&Bh[(long)(col0 + r) * 128 + k0 + q * 8], &Bsh[seg * 512]);
            glds16(&Bl[(long)(col0 + r) * 128 + k0 + q * 8], &Bsl[seg * 512]);
        }
        __syncthreads();

        bf16x8 af[2][4], bg[2][4];
#pragma unroll
        for (int i = 0; i < 4; ++i) {
            int rA = wr + i * 16 + m;
            int pA = quad ^ ((rA >> 1) & 3);
            af[0][i] = *(const bf16x8*)&Ash[rA * 32 + pA * 8];
            af[1][i] = *(const bf16x8*)&Asl[rA * 32 + pA * 8];
            int rB = wc + i * 16 + m;
            int pB = quad ^ ((rB >> 1) & 3);
            bg[0][i] = *(const bf16x8*)&Bsh[rB * 32 + pB * 8];
            bg[1][i] = *(const bf16x8*)&Bsl[rB * 32 + pB * 8];
        }
#pragma unroll
        for (int i = 0; i < 4; ++i)
#pragma unroll
            for (int j = 0; j < 4; ++j) {
                acc[i][j] = __builtin_amdgcn_mfma_f32_16x16x32_bf16(af[0][i], bg[0][j], acc[i][j], 0, 0, 0);
                acc[i][j] = __builtin_amdgcn_mfma_f32_16x16x32_bf16(af[0][i], bg[1][j], acc[i][j], 0, 0, 0);
                acc[i][j] = __builtin_amdgcn_mfma_f32_16x16x32_bf16(af[1][i], bg[0][j], acc[i][j], 0, 0, 0);
            }
        __syncthreads();
    }

    float bv[4];
#pragma unroll
    for (int j = 0; j < 4; ++j) bv[j] = bias[col0 + wc + j * 16 + m];
    float* outb = out + bz * (8192L * 256);
#pragma unroll
    for (int i = 0; i < 4; ++i)
#pragma unroll
        for (int r4 = 0; r4 < 4; ++r4) {
            long row = row0 + wr + i * 16 + quad * 4 + r4;
#pragma unroll
            for (int j = 0; j < 4; ++j)
                outb[row * 256 + col0 + wc + j * 16 + m] = acc[i][j][r4] + bv[j];
        }
}

extern "C" void kernel_launch(void* const* d_in, const int* in_sizes, int n_in,
                              void* d_out, int out_size, void* d_ws, size_t ws_size,
                              hipStream_t stream) {
    const float* x     = (const float*)d_in[0];
    const float* W_qkv = (const float*)d_in[1];
    const float* W_out = (const float*)d_in[2];
    const float* b_out = (const float*)d_in[3];
    float* out = (float*)d_out;

    char* p = (char*)d_ws;
    float* kv   = (float*)p;  p += (long)64 * 8192 * 64 * 4;   // head-blocked [bh][l][k32|v32]
    float* S    = (float*)p;  p += 65536 * 4;
    float* Z    = (float*)p;  p += 2048 * 4;
    ushort* wth = (ushort*)p; p += 384 * 256 * 2;
    ushort* wtl = (ushort*)p; p += 384 * 256 * 2;
    ushort* qh  = (ushort*)p; p += (long)BL * 128 * 2;
    ushort* ql  = (ushort*)p; p += (long)BL * 128 * 2;
    ushort* m2h = (ushort*)p; p += 16 * 256 * 128 * 2;
    ushort* m2l = (ushort*)p; p += 16 * 256 * 128 * 2;

    init_stats<<<264, 256, 0, stream>>>(S, Z);
    convert_w<<<384, 256, 0, stream>>>(W_qkv, wth, wtl);

    gemm1_kernel<<<3072, 256, 0, stream>>>(x, wth, wtl, qh, ql, kv);

    ksum_hb<<<512, 256, 0, stream>>>(kv, S, Z);
    combine_kernel<<<64, 256, 0, stream>>>(S, Z, W_out, m2h, m2l);

    gemm2_kernel<<<dim3(2, 64, 16), 256, 0, stream>>>(qh, ql, m2h, m2l, b_out, out);
}

// Round 2
// 429.018 us; speedup vs baseline: 1.0192x; 1.0053x over previous
//
#include <hip/hip_runtime.h>
#include <math.h>

// LinearAttention B=16 L=8192 D=256 H=4 dh=32
//   gemm1 (split-bf16 MFMA, prefetch-dbuf pipeline): qkv = x@W_qkv
//     colblk 0 -> q hi/lo bf16 [BL,128]
//     colblk 1 -> k fp32 into kvhb[bh][l][0..31]
//     colblk 2 -> v fp32 into kvhb[bh][l][32..63]
//     XCD-grouped grid: 3 col-blocks of one row-block share an XCD's L2
//   ksum (register-blocked 4dx8e per thread): S[d,e]=sum_l e^k v, Z_d=sum_l e^k
//   combine: M2T[b][n][c] = scale * (S/Z) @ W_out   (split hi/lo bf16)
//   gemm2 (split-bf16 MFMA, prefetch-dbuf): out[b] = q[b]@M2[b] + b_out
// Pipeline (T3-minimum): STAGE(next buf) issued BEFORE compute(cur); single
// __syncthreads (vmcnt drain) per k-step -> HBM latency hides under MFMA.

#define BL 131072

typedef __attribute__((ext_vector_type(8))) short bf16x8;
typedef __attribute__((ext_vector_type(4))) float f32x4;
typedef __attribute__((ext_vector_type(4))) unsigned u32x4;

__device__ __forceinline__ unsigned cvt_pk2(float a, float b) {
    unsigned r;
    asm("v_cvt_pk_bf16_f32 %0, %1, %2" : "=v"(r) : "v"(a), "v"(b));
    return r;
}
__device__ __forceinline__ ushort bf16_rn(float f) {
    return (ushort)cvt_pk2(f, f);
}
__device__ __forceinline__ float bf16f(ushort h) { return __uint_as_float(((unsigned)h) << 16); }

__device__ __forceinline__ void glds16(const void* g, void* l) {
    __builtin_amdgcn_global_load_lds((const __attribute__((address_space(1))) unsigned int*)g,
                                     (__attribute__((address_space(3))) unsigned int*)l,
                                     16, 0, 0);
}

// merged: W_qkv [256,384] -> WT hi/lo bf16 [384,256]  +  zero S/Z
__global__ __launch_bounds__(256) void prep_kernel(const float* __restrict__ W,
                                                   ushort* __restrict__ wh,
                                                   ushort* __restrict__ wl,
                                                   float* __restrict__ S,
                                                   float* __restrict__ Z) {
    int n = blockIdx.x, k = threadIdx.x;
    float f = W[k * 384 + n];
    ushort h = bf16_rn(f);
    wh[n * 256 + k] = h;
    wl[n * 256 + k] = bf16_rn(f - bf16f(h));
    int i = n * 256 + k;
    if (i < 65536) S[i] = 0.f;
    if (i < 2048) Z[i] = 0.f;
}

// gemm1: [131072x256] @ [256x384], A fp32 (split in-kernel), B=WT hi/lo bf16.
// grid 3072 (1D): xcd = wg&7, slot = wg>>3, cb = slot%3, yb = (slot/3)*8+xcd.
__global__ __launch_bounds__(256) void gemm1_kernel(
    const float* __restrict__ X,
    const ushort* __restrict__ Wh, const ushort* __restrict__ Wl,
    ushort* __restrict__ Qh, ushort* __restrict__ Ql,
    float* __restrict__ KV) {
    __shared__ __align__(16) float  As[2][4096];   // 128r x 32k fp32, chunk p = q ^ (r&7)
    __shared__ __align__(16) ushort Bsh[2][4096];  // 128r x 32k bf16, chunk p = q ^ ((r>>1)&3)
    __shared__ __align__(16) ushort Bsl[2][4096];
    const int tid = threadIdx.x;
    const int wg = blockIdx.x;
    const int xcd = wg & 7;
    const int slot = wg >> 3;
    const int cb = slot % 3;
    const int yb = (slot / 3) * 8 + xcd;
    const int col0 = cb * 128;
    const int row0 = yb * 128;
    const int lane = tid & 63, wave = tid >> 6;
    const int wr = (wave & 1) * 64, wc = (wave >> 1) * 64;
    const int m = lane & 15, quad = lane >> 4;
    const int ra = lane >> 3, pa = lane & 7;   // A staging: 8 rows/seg, 8 chunks(16B)/row
    const int rb = lane >> 2, pb = lane & 3;   // B staging: 16 rows/seg, 4 chunks/row

    f32x4 acc[4][4] = {};

    auto STAGE = [&](int buf, int k0) {
#pragma unroll
        for (int s = 0; s < 4; ++s) {          // A: 16 segs of 1KB
            int seg = s * 4 + wave;
            int r = seg * 8 + ra;
            int q = pa ^ (r & 7);
            glds16(&X[(long)(row0 + r) * 256 + k0 + q * 4], &As[buf][seg * 256]);
        }
#pragma unroll
        for (int s = 0; s < 2; ++s) {          // Bh/Bl: 8 segs each
            int seg = s * 4 + wave;
            int r = seg * 16 + rb;
            int q = pb ^ ((r >> 1) & 3);
            glds16(&Wh[(long)(col0 + r) * 256 + k0 + q * 8], &Bsh[buf][seg * 512]);
            glds16(&Wl[(long)(col0 + r) * 256 + k0 + q * 8], &Bsl[buf][seg * 512]);
        }
    };

    STAGE(0, 0);
    __syncthreads();

    for (int kt = 0; kt < 8; ++kt) {
        const int cur = kt & 1;
        if (kt < 7) STAGE(cur ^ 1, (kt + 1) * 32);   // prefetch next tile (in flight over MFMA)

        bf16x8 bh[4], bl[4];
#pragma unroll
        for (int i = 0; i < 4; ++i) {
            int r = wc + i * 16 + m;
            int p = quad ^ ((r >> 1) & 3);
            bh[i] = *(const bf16x8*)&Bsh[cur][r * 32 + p * 8];
            bl[i] = *(const bf16x8*)&Bsl[cur][r * 32 + p * 8];
        }
#pragma unroll
        for (int i = 0; i < 4; ++i) {
            int r = wr + i * 16 + m;
            int p0 = (quad * 2) ^ (r & 7);
            int p1 = (quad * 2 + 1) ^ (r & 7);
            f32x4 a0 = *(const f32x4*)&As[cur][r * 32 + p0 * 4];
            f32x4 a1 = *(const f32x4*)&As[cur][r * 32 + p1 * 4];
            u32x4 ahw, alw;
#pragma unroll
            for (int e = 0; e < 2; ++e) {
                float f0 = a0[2 * e], f1 = a0[2 * e + 1];
                unsigned h = cvt_pk2(f0, f1);
                ahw[e] = h;
                alw[e] = cvt_pk2(f0 - __uint_as_float(h << 16),
                                 f1 - __uint_as_float(h & 0xFFFF0000u));
            }
#pragma unroll
            for (int e = 0; e < 2; ++e) {
                float f0 = a1[2 * e], f1 = a1[2 * e + 1];
                unsigned h = cvt_pk2(f0, f1);
                ahw[2 + e] = h;
                alw[2 + e] = cvt_pk2(f0 - __uint_as_float(h << 16),
                                     f1 - __uint_as_float(h & 0xFFFF0000u));
            }
            bf16x8 ah = __builtin_bit_cast(bf16x8, ahw);
            bf16x8 al = __builtin_bit_cast(bf16x8, alw);
#pragma unroll
            for (int j = 0; j < 4; ++j) {
                acc[i][j] = __builtin_amdgcn_mfma_f32_16x16x32_bf16(ah, bh[j], acc[i][j], 0, 0, 0);
                acc[i][j] = __builtin_amdgcn_mfma_f32_16x16x32_bf16(ah, bl[j], acc[i][j], 0, 0, 0);
                acc[i][j] = __builtin_amdgcn_mfma_f32_16x16x32_bf16(al, bh[j], acc[i][j], 0, 0, 0);
            }
        }
        __syncthreads();   // drains prefetch vmcnt + frees cur buffer
    }

    if (cb == 0) {                   // q -> hi/lo bf16 [BL,128]
#pragma unroll
        for (int i = 0; i < 4; ++i)
#pragma unroll
            for (int r4 = 0; r4 < 4; ++r4) {
                long row = row0 + wr + i * 16 + quad * 4 + r4;
#pragma unroll
                for (int j = 0; j < 4; ++j) {
                    float v = acc[i][j][r4];
                    int col = wc + j * 16 + m;
                    ushort h = bf16_rn(v);
                    Qh[row * 128 + col] = h;
                    Ql[row * 128 + col] = bf16_rn(v - bf16f(h));
                }
            }
    } else {                         // k (cb=1) / v (cb=2) -> kvhb[bh][l][64]
        int vofs = (cb == 2) ? 32 : 0;
#pragma unroll
        for (int i = 0; i < 4; ++i)
#pragma unroll
            for (int r4 = 0; r4 < 4; ++r4) {
                long row = row0 + wr + i * 16 + quad * 4 + r4;
                long b = row >> 13, l = row & 8191;
#pragma unroll
                for (int j = 0; j < 4; ++j) {
                    int c = wc + j * 16 + m;
                    int h = c >> 5, dd = c & 31;
                    KV[(((b * 4 + h) * 8192 + l) * 64) + vofs + dd] = acc[i][j][r4];
                }
            }
    }
}

// S[d,e] = sum_l e^{k[l,d]} v[l,e]; Z_d = sum_l e^{k}. grid = bh*8+chunk (512 blocks).
// Register-blocked: thread owns 4d x 8e outputs, 1/8 of the l's; 3 ds_read_b128/l.
// LDS layout: idx(l,c) = l*64 + (l>>3)*4 + c  (16B aligned, lg spreads banks).
__global__ __launch_bounds__(256) void ksum_hb(const float* __restrict__ KV,
                                               float* __restrict__ S,
                                               float* __restrict__ Z) {
    int bx = blockIdx.x;
    int chunk = bx & 7, bh = bx >> 3;
    const float* slab = KV + ((long)bh * 8192 + chunk * 1024) * 64;
    __shared__ float tile[4128];
    const int tid = threadIdx.x;
    const int w = tid >> 6, lane = tid & 63;
    const int lg = lane >> 3, cc = lane & 7;
    const int combo = w * 8 + cc;        // 0..31 -> (dq, eo)
    const int d0 = (combo >> 2) * 4;
    const int e0 = (combo & 3) * 8;
    const int c4 = tid & 15, lrow = tid >> 4;   // loader: float4 id
    float z4[4] = {0.f, 0.f, 0.f, 0.f};
    float acc[4][8] = {};

    for (int t0 = 0; t0 < 1024; t0 += 64) {
#pragma unroll
        for (int u = 0; u < 4; ++u) {
            int l = u * 16 + lrow;
            float4 wv = *(const float4*)&slab[((long)(t0 + l)) * 64 + c4 * 4];
            if (c4 < 8) { wv.x = __expf(wv.x); wv.y = __expf(wv.y); wv.z = __expf(wv.z); wv.w = __expf(wv.w); }
            *(float4*)&tile[l * 64 + (l >> 3) * 4 + c4 * 4] = wv;
        }
        __syncthreads();
#pragma unroll
        for (int j = 0; j < 8; ++j) {
            int l = lg * 8 + j;
            int base = l * 64 + lg * 4;
            f32x4 ev = *(const f32x4*)&tile[base + d0];
            f32x4 v0 = *(const f32x4*)&tile[base + 32 + e0];
            f32x4 v1 = *(const f32x4*)&tile[base + 36 + e0];
#pragma unroll
            for (int q = 0; q < 4; ++q) {
                float e = ev[q];
                z4[q] += e;
                acc[q][0] += e * v0[0]; acc[q][1] += e * v0[1];
                acc[q][2] += e * v0[2]; acc[q][3] += e * v0[3];
                acc[q][4] += e * v1[0]; acc[q][5] += e * v1[1];
                acc[q][6] += e * v1[2]; acc[q][7] += e * v1[3];
            }
        }
        __syncthreads();
    }
    // reduce over lg (lane bits 3..5)
#pragma unroll
    for (int q = 0; q < 4; ++q) {
        z4[q] += __shfl_xor(z4[q], 8);
        z4[q] += __shfl_xor(z4[q], 16);
        z4[q] += __shfl_xor(z4[q], 32);
#pragma unroll
        for (int j = 0; j < 8; ++j) {
            acc[q][j] += __shfl_xor(acc[q][j], 8);
            acc[q][j] += __shfl_xor(acc[q][j], 16);
            acc[q][j] += __shfl_xor(acc[q][j], 32);
        }
    }
    if (lg == 0) {
#pragma unroll
        for (int q = 0; q < 4; ++q)
#pragma unroll
            for (int j = 0; j < 8; ++j)
                atomicAdd(&S[((long)bh * 32 + d0 + q) * 32 + e0 + j], acc[q][j]);
        if ((cc & 3) == 0)
#pragma unroll
            for (int q = 0; q < 4; ++q)
                atomicAdd(&Z[bh * 32 + d0 + q], z4[q]);
    }
}

// M2T[b][n][h*32+d] = scale * (S[d,e]/Z_d) @ W_out[h*32+e, n], split hi/lo. grid B*H.
__global__ __launch_bounds__(256) void combine_kernel(const float* __restrict__ S,
                                                      const float* __restrict__ Z,
                                                      const float* __restrict__ Wout,
                                                      ushort* __restrict__ m2h,
                                                      ushort* __restrict__ m2l) {
    int bh = blockIdx.x;
    int b = bh >> 2, h = bh & 3;
    int n = threadIdx.x;
    __shared__ float ctx[32][32];
    __shared__ float zs[32];
    if (n < 32) zs[n] = Z[bh * 32 + n];
    __syncthreads();
#pragma unroll
    for (int t = 0; t < 4; ++t) {
        int idx = t * 256 + n;
        int d = idx >> 5, e = idx & 31;
        ctx[d][e] = S[(long)bh * 1024 + idx] / zs[d];
    }
    __syncthreads();
    const float scale = 0.17677669529663687f; // 1/sqrt(32)
    float acc[32];
#pragma unroll
    for (int d = 0; d < 32; ++d) acc[d] = 0.f;
    for (int e = 0; e < 32; ++e) {
        float w = Wout[(h * 32 + e) * 256 + n];
#pragma unroll
        for (int d = 0; d < 32; ++d) acc[d] += ctx[d][e] * w;
    }
#pragma unroll
    for (int d = 0; d < 32; ++d) {
        float v = acc[d] * scale;
        long idx = ((long)(b * 256 + n)) * 128 + h * 32 + d;
        ushort hh = bf16_rn(v);
        m2h[idx] = hh;
        m2l[idx] = bf16_rn(v - bf16f(hh));
    }
}

// gemm2: per-b [8192x128] @ [128x256] + bias. A=q hi/lo, B=M2T hi/lo (both [N][K] bf16).
// grid 2048 (1D): xcd = bid&7, u = bid>>3, cb = u&1, id = (u>>1)*8+xcd -> (bz, yb).
// Both col-blocks of one (bz,yb) share an XCD (q panel L2-reuse).
__global__ __launch_bounds__(256) void gemm2_kernel(
    const ushort* __restrict__ Ahp, const ushort* __restrict__ Alp,
    const ushort* __restrict__ Bhp, const ushort* __restrict__ Blp,
    const float* __restrict__ bias, float* __restrict__ out) {
    __shared__ __align__(16) ushort Ash[2][4096];
    __shared__ __align__(16) ushort Asl[2][4096];
    __shared__ __align__(16) ushort Bsh[2][4096];
    __shared__ __align__(16) ushort Bsl[2][4096];
    const int tid = threadIdx.x;
    const int bid = blockIdx.x;
    const int xcd = bid & 7;
    const int u = bid >> 3;
    const int cbl = u & 1;
    const int id = (u >> 1) * 8 + xcd;       // 0..1023
    const int col0 = cbl * 128;
    const int row0 = (id & 63) * 128;
    const long bz = id >> 6;
    const ushort* Ah = Ahp + bz * (8192L * 128);
    const ushort* Al = Alp + bz * (8192L * 128);
    const ushort* Bh = Bhp + bz * (256L * 128);
    const ushort* Bl = Blp + bz * (256L * 128);
    const int lane = tid & 63, wave = tid >> 6;
    const int wr = (wave & 1) * 64, wc = (wave >> 1) * 64;
    const int m = lane & 15, quad = lane >> 4;
    const int rb = lane >> 2, pb = lane & 3;

    f32x4 acc[4][4] = {};

    auto STAGE = [&](int buf, int k0) {
#pragma unroll
        for (int s = 0; s < 2; ++s) {
            int seg = s * 4 + wave;
            int r = seg * 16 + rb;
            int q = pb ^ ((r >> 1) & 3);
            glds16(&Ah[(long)(row0 + r) * 128 + k0 + q * 8], &Ash[buf][seg * 512]);
            glds16(&Al[(long)(row0 + r) * 128 + k0 + q * 8], &Asl[buf][seg * 512]);
            glds16(&Bh[(long)(col0 + r) * 128 + k0 + q * 8], &Bsh[buf][seg * 512]);
            glds16(&Bl[(long)(col0 + r) * 128 + k0 + q * 8], &Bsl[buf][seg * 512]);
        }
    };

    STAGE(0, 0);
    __syncthreads();

    for (int kt = 0; kt < 4; ++kt) {
        const int cur = kt & 1;
        if (kt < 3) STAGE(cur ^ 1, (kt + 1) * 32);

        bf16x8 af[2][4], bg[2][4];
#pragma unroll
        for (int i = 0; i < 4; ++i) {
            int rA = wr + i * 16 + m;
            int pA = quad ^ ((rA >> 1) & 3);
            af[0][i] = *(const bf16x8*)&Ash[cur][rA * 32 + pA * 8];
            af[1][i] = *(const bf16x8*)&Asl[cur][rA * 32 + pA * 8];
            int rB = wc + i * 16 + m;
            int pB = quad ^ ((rB >> 1) & 3);
            bg[0][i] = *(const bf16x8*)&Bsh[cur][rB * 32 + pB * 8];
            bg[1][i] = *(const bf16x8*)&Bsl[cur][rB * 32 + pB * 8];
        }
#pragma unroll
        for (int i = 0; i < 4; ++i)
#pragma unroll
            for (int j = 0; j < 4; ++j) {
                acc[i][j] = __builtin_amdgcn_mfma_f32_16x16x32_bf16(af[0][i], bg[0][j], acc[i][j], 0, 0, 0);
                acc[i][j] = __builtin_amdgcn_mfma_f32_16x16x32_bf16(af[0][i], bg[1][j], acc[i][j], 0, 0, 0);
                acc[i][j] = __builtin_amdgcn_mfma_f32_16x16x32_bf16(af[1][i], bg[0][j], acc[i][j], 0, 0, 0);
            }
        __syncthreads();
    }

    float bv[4];
#pragma unroll
    for (int j = 0; j < 4; ++j) bv[j] = bias[col0 + wc + j * 16 + m];
    float* outb = out + bz * (8192L * 256);
#pragma unroll
    for (int i = 0; i < 4; ++i)
#pragma unroll
        for (int r4 = 0; r4 < 4; ++r4) {
            long row = row0 + wr + i * 16 + quad * 4 + r4;
#pragma unroll
            for (int j = 0; j < 4; ++j)
                outb[row * 256 + col0 + wc + j * 16 + m] = acc[i][j][r4] + bv[j];
        }
}

extern "C" void kernel_launch(void* const* d_in, const int* in_sizes, int n_in,
                              void* d_out, int out_size, void* d_ws, size_t ws_size,
                              hipStream_t stream) {
    const float* x     = (const float*)d_in[0];
    const float* W_qkv = (const float*)d_in[1];
    const float* W_out = (const float*)d_in[2];
    const float* b_out = (const float*)d_in[3];
    float* out = (float*)d_out;

    char* p = (char*)d_ws;
    float* kv   = (float*)p;  p += (long)64 * 8192 * 64 * 4;   // head-blocked [bh][l][k32|v32]
    float* S    = (float*)p;  p += 65536 * 4;
    float* Z    = (float*)p;  p += 2048 * 4;
    ushort* wth = (ushort*)p; p += 384 * 256 * 2;
    ushort* wtl = (ushort*)p; p += 384 * 256 * 2;
    ushort* qh  = (ushort*)p; p += (long)BL * 128 * 2;
    ushort* ql  = (ushort*)p; p += (long)BL * 128 * 2;
    ushort* m2h = (ushort*)p; p += 16 * 256 * 128 * 2;
    ushort* m2l = (ushort*)p; p += 16 * 256 * 128 * 2;

    prep_kernel<<<384, 256, 0, stream>>>(W_qkv, wth, wtl, S, Z);

    gemm1_kernel<<<3072, 256, 0, stream>>>(x, wth, wtl, qh, ql, kv);

    ksum_hb<<<512, 256, 0, stream>>>(kv, S, Z);
    combine_kernel<<<64, 256, 0, stream>>>(S, Z, W_out, m2h, m2l);

    gemm2_kernel<<<2048, 256, 0, stream>>>(qh, ql, m2h, m2l, b_out, out);
}